// Round 6
// baseline (71.431 us; speedup 1.0000x reference)
//
#include <hip/hip_runtime.h>
#include <math.h>

// yoloHeadv3: X (B,255,52,52) f32  ->  out (B, 3*52*52, 85) f32
// B=64, A=3 anchors, C=80 classes, G=52, ratio = 416/52 = 8.
//
// Round 6: TILE = 52 (one grid row i per block).
//  - all tiles full -> no tail divergence, single code path
//  - i = tile, j = local index -> no % / div for grid coords
//  - LDS 17680 B -> 8 blocks/CU (32/32 waves theoretical occupancy, was 7)
// Keeps: flat LDS in exact output order (lds[j*85+k]), linear store phase
// with nontemporal dwordx4 stores (write-once output must not evict X from
// the 256 MB Infinity Cache).

constexpr int G    = 52;
constexpr int GG   = G * G;          // 2704
constexpr int NA   = 3;
constexpr int NC   = 85;             // channels per anchor
constexpr int TILE = G;              // 52 ij per block = one row i
constexpr int NT   = GG / TILE;      // 52 tiles, all full
constexpr int NV   = TILE / 4;       // 13 float4 per channel row
constexpr int ITEMS = NC * NV;       // 1105 load items
constexpr int WORDS = TILE * NC;     // 4420 floats in LDS
constexpr int VOUT  = WORDS / 4;     // 1105 float4 stores
constexpr float RATIO = 8.0f;

typedef float f32x4 __attribute__((ext_vector_type(4)));

__device__ __forceinline__ float sigmoidf_(float v) {
    return 1.0f / (1.0f + expf(-v));
}

__device__ __forceinline__ float transform_(float v, int c, float fj, float fi,
                                            float ax, float ay) {
    if (c >= 5) return v;                                   // classes: passthrough
    if (c == 0) return (sigmoidf_(v) + fj) * RATIO;         // bx
    if (c == 1) return (sigmoidf_(v) + fi) * RATIO;         // by
    if (c == 2) return fminf(expf(v), 1000.0f) * ax;        // bw (scale folds exactly)
    if (c == 3) return fminf(expf(v), 1000.0f) * ay;        // bh
    return sigmoidf_(v);                                    // conf
}

__global__ __launch_bounds__(256)
void yolo_head_kernel(const float* __restrict__ X, float* __restrict__ out) {
    __shared__ float lds[WORDS];     // 17680 B, word = j*85 + k (output order)

    const int bid  = blockIdx.x;
    const int tile = bid % NT;       // grid row i
    const int ba   = bid / NT;
    const int a    = ba % NA;
    const int b    = ba / NA;

    const float fi = (float)tile;
    const float ax = (a == 0) ? 116.0f : ((a == 1) ? 156.0f : 373.0f);
    const float ay = (a == 0) ?  90.0f : ((a == 1) ? 198.0f : 326.0f);

    const f32x4* src = reinterpret_cast<const f32x4*>(
        X + ((size_t)(b * NA + a) * NC) * GG + (size_t)tile * TILE);
    const int srow = GG / 4;         // 676 float4 per channel

    const int tid = threadIdx.x;

    // ---- load phase: coalesced float4 reads, transform, scatter to LDS ----
    #pragma unroll
    for (int it = 0; it < 5; ++it) {
        const int idx = tid + it * 256;
        if (it < 4 || idx < ITEMS) {
            const int c  = idx / NV;         // magic-mul (NV=13 const)
            const int v4 = idx - c * NV;
            f32x4 val = src[(size_t)c * srow + v4];
            const int j0 = v4 << 2;
            #pragma unroll
            for (int m = 0; m < 4; ++m) {
                lds[(j0 + m) * NC + c] =
                    transform_(val[m], c, (float)(j0 + m), fi, ax, ay);
            }
        }
    }

    __syncthreads();

    // ---- store phase: linear LDS -> global, nt dwordx4, zero addr math ----
    f32x4* dst4 = reinterpret_cast<f32x4*>(
        out + ((size_t)(b * NA + a) * GG + (size_t)tile * TILE) * NC);
    const f32x4* lds4 = reinterpret_cast<const f32x4*>(lds);

    #pragma unroll
    for (int it = 0; it < 5; ++it) {
        const int idx = tid + it * 256;
        if (it < 4 || idx < VOUT) {
            __builtin_nontemporal_store(lds4[idx], &dst4[idx]);
        }
    }
}

extern "C" void kernel_launch(void* const* d_in, const int* in_sizes, int n_in,
                              void* d_out, int out_size, void* d_ws, size_t ws_size,
                              hipStream_t stream) {
    const float* X = (const float*)d_in[0];
    float* out = (float*)d_out;
    const int B = in_sizes[0] / (NA * NC * GG);   // 64
    dim3 grid((unsigned)(B * NA * NT));
    yolo_head_kernel<<<grid, dim3(256), 0, stream>>>(X, out);
}

// Round 7
// 64.754 us; speedup vs baseline: 1.1031x; 1.1031x over previous
//
#include <hip/hip_runtime.h>
#include <math.h>

// yoloHeadv3: X (B,255,52,52) f32  ->  out (B, 3*52*52, 85) f32
// B=64, A=3 anchors, C=80 classes, G=52, ratio = 416/52 = 8.
//
// Round 7: barrier-free wave-local transpose.
//   Each WAVE owns 16 output rows (one wave-tile): loads 85 ch x 16 floats
//   (16 x 64B segments, coalesced), transforms ch 0..4, scatters into a
//   wave-private LDS slice (stride-85 words), then stores 340 contiguous
//   nontemporal float4 (5440 B). No __syncthreads: DS ops from one wave
//   execute in order, so same-wave read-after-write is safe; an asm memory
//   clobber prevents compiler reordering. Waves are fully decoupled ->
//   stores issue as soon as each wave's own loads land.
//   32448 wave-tiles enumerated globally -> 8112 blocks, zero idle waves.
//   All global offsets stay 64B+ aligned (tile row-chunk = 64B, out = 5440B).

constexpr int G   = 52;
constexpr int GG  = G * G;            // 2704
constexpr int NA  = 3;
constexpr int NC  = 85;               // channels per anchor
constexpr int RPW = 16;               // rows (ij positions) per wave
constexpr int WTB = GG / RPW;         // 169 wave-tiles per (b,a)
constexpr float RATIO = 8.0f;

typedef float f32x4 __attribute__((ext_vector_type(4)));

__device__ __forceinline__ float sigmoidf_(float v) {
    return 1.0f / (1.0f + expf(-v));
}

__global__ __launch_bounds__(256)
void yolo_head_kernel(const float* __restrict__ X, float* __restrict__ out,
                      int total_wt) {
    __shared__ float lds[4 * RPW * NC];      // 4 waves * 1360 words = 21760 B

    const int w    = threadIdx.x >> 6;
    const int lane = threadIdx.x & 63;
    const int t    = blockIdx.x * 4 + w;     // global wave-tile id
    if (t >= total_wt) return;

    const int ba  = t / WTB;                 // b*NA + a   (compiler magic-div)
    const int rem = t - ba * WTB;
    const int ij0 = rem * RPW;               // first ij of this wave-tile

    const int a = ba % NA;
    const float ax = (a == 0) ? 116.0f : ((a == 1) ? 156.0f : 373.0f);
    const float ay = (a == 0) ?  90.0f : ((a == 1) ? 198.0f : 326.0f);

    const f32x4* src = reinterpret_cast<const f32x4*>(X)
                       + (size_t)ba * NC * (GG / 4) + (ij0 >> 2);
    float* ldsw = lds + w * (RPW * NC);

    const int c0 = lane >> 2;                // channel offset within it-group
    const int v4 = lane & 3;                 // which float4 of the 16-row chunk
    const int jl = v4 << 2;

    // ---- load: 85 ch x 4 float4 = 340 items; it=5 has 20 active lanes ----
    #pragma unroll
    for (int it = 0; it < 6; ++it) {
        if (it < 5 || lane < 20) {
            const int c = it * 16 + c0;
            f32x4 val = src[(size_t)c * (GG / 4) + v4];
            if (it == 0 && lane < 20) {      // c in 0..4: special channels
                #pragma unroll
                for (int m = 0; m < 4; ++m) {
                    const int ij = ij0 + jl + m;
                    const float v = val[m];
                    float r;
                    if (c == 0)      r = (sigmoidf_(v) + (float)(ij % G)) * RATIO;
                    else if (c == 1) r = (sigmoidf_(v) + (float)(ij / G)) * RATIO;
                    else if (c == 2) r = fminf(expf(v), 1000.0f) * ax;
                    else if (c == 3) r = fminf(expf(v), 1000.0f) * ay;
                    else             r = sigmoidf_(v);
                    ldsw[(jl + m) * NC + c] = r;
                }
            } else {                         // classes: passthrough
                #pragma unroll
                for (int m = 0; m < 4; ++m)
                    ldsw[(jl + m) * NC + c] = val[m];
            }
        }
    }

    // Same-wave LDS RAW is ordered by HW; stop compiler reordering only.
    asm volatile("" ::: "memory");

    // ---- store: 340 contiguous nt float4 (wave-private slice) ----
    const f32x4* lds4 = reinterpret_cast<const f32x4*>(ldsw);
    f32x4* dst4 = reinterpret_cast<f32x4*>(out)
                  + (size_t)ba * (GG * NC / 4) + (size_t)rem * (RPW * NC / 4);
    #pragma unroll
    for (int it = 0; it < 6; ++it) {
        const int idx = it * 64 + lane;
        if (it < 5 || lane < 20) {
            __builtin_nontemporal_store(lds4[idx], &dst4[idx]);
        }
    }
}

extern "C" void kernel_launch(void* const* d_in, const int* in_sizes, int n_in,
                              void* d_out, int out_size, void* d_ws, size_t ws_size,
                              hipStream_t stream) {
    const float* X = (const float*)d_in[0];
    float* out = (float*)d_out;
    const int B = in_sizes[0] / (NA * NC * GG);       // 64
    const int total_wt = B * NA * WTB;                // 32448
    const int blocks = (total_wt + 3) / 4;            // 8112
    yolo_head_kernel<<<dim3((unsigned)blocks), dim3(256), 0, stream>>>(X, out, total_wt);
}